// Round 11
// baseline (1125.066 us; speedup 1.0000x reference)
//
#include <hip/hip_runtime.h>

#define EDGES 400000
#define DIM 128

typedef __attribute__((ext_vector_type(8))) short bf16x8;
typedef __attribute__((ext_vector_type(4))) float f32x4;

// fp32 -> bf16 round-to-nearest-even (no NaN handling needed here)
__device__ __forceinline__ short f2bf(float f) {
    unsigned u = __builtin_bit_cast(unsigned, f);
    unsigned r = (u + 0x7fffu + ((u >> 16) & 1u)) >> 16;
    return (short)r;
}

// Rearrange W1 [768][384] fp32 -> bf16 frag-major for 16x16x32 MFMA B-operand:
// frag (nt, s): lane holds B[k = (lane>>4)*8 + j][n = lane&15], k-step s, n-tile nt.
// W1f[((nt*12+s)*64+lane)*8 + j] = bf16( W1[(nt*16+(lane&15))*384 + s*32+(lane>>4)*8+j] )
__global__ void prep_w1(const float* __restrict__ W1, short* __restrict__ W1f) {
    int idx = blockIdx.x * 256 + threadIdx.x;       // 294912 = 48*12*64*8
    int j    = idx & 7;
    int lane = (idx >> 3) & 63;
    int fs   = idx >> 9;                            // nt*12 + s
    int s    = fs % 12;
    int nt   = fs / 12;
    int n = nt * 16 + (lane & 15);
    int k = s * 32 + (lane >> 4) * 8 + j;
    W1f[idx] = f2bf(W1[n * 384 + k]);
}

// Block: 256 threads = 4 waves, 128 edges (each wave owns 2 M-tiles of 16 edges).
// NO LDS STAGING: W1f is 576 KB = fully L2-resident (4MB/XCD), and the block's
// waves share each 12KB nt-chunk through L1 (32KB). Staging an L2-fit operand
// through LDS was pure overhead (Common-mistake #7; m169 attn: +26% from
// dropping it). Round-0 budget/CU-round: ds_read 1152cy (busiest pipe, 48%),
// MFMA 931cy, VALU 640cy. Direct global->reg B-loads move that traffic to the
// VMEM pipe (L1/L2-hit, coalesced 16B/lane), eliminate the per-nt barrier +
// vmcnt drain + staging instructions, and free LDS -> 4 blocks/CU (16 waves)
// for latency hiding. Waves are fully independent (no __syncthreads at all).
// Round-10 lesson: rotation/setprio scheduling games regress; keep it simple.
__global__ __launch_bounds__(256)
void edge_mlp(const float* __restrict__ x,
              const int*   __restrict__ ei,      // [2][EDGES]
              const float* __restrict__ b1,      // [768]
              const float* __restrict__ W2,      // [768]
              const float* __restrict__ b2p,     // [1]
              const short* __restrict__ W1f,     // frag-major bf16 W1
              float* __restrict__ out)           // [EDGES]
{
    const int tid  = threadIdx.x;
    const int lane = tid & 63;
    const int wave = tid >> 6;
    const int m    = lane & 15;                  // A-row / B-col / D-col index
    const int quad = lane >> 4;
    const int eb   = blockIdx.x * 128;

    // ---- build A fragments in registers: 2 M-tiles x 12 K-steps (96 VGPRs) ----
    // A-frag layout (m89/m120-verified): lane holds A[m=lane&15][k=quad*8+j].
    // feat col kc = 32*s + 8*quad + j ; sections: s 0-3 mean, 4-7 prod, 8-11 sqdiff,
    // all three from the SAME x columns -> each x chunk loaded once.
    bf16x8 afrag[2][12];
    #pragma unroll
    for (int T = 0; T < 2; ++T) {
        int e = eb + wave * 32 + T * 16 + m;
        const float* r0 = x + (size_t)ei[e] * DIM;
        const float* r1 = x + (size_t)ei[EDGES + e] * DIM;
        #pragma unroll
        for (int i = 0; i < 4; ++i) {
            int c = i * 32 + quad * 8;
            f32x4 a0 = *(const f32x4*)(r0 + c);
            f32x4 a1 = *(const f32x4*)(r0 + c + 4);
            f32x4 c0 = *(const f32x4*)(r1 + c);
            f32x4 c1 = *(const f32x4*)(r1 + c + 4);
            bf16x8 fm, fp, fd;
            #pragma unroll
            for (int j = 0; j < 4; ++j) {
                float aa = a0[j], bb = c0[j];
                fm[j] = f2bf((aa + bb) * 0.5f);
                fp[j] = f2bf(aa * bb);
                float dd = aa - bb;
                fd[j] = f2bf(dd * dd);
                aa = a1[j]; bb = c1[j];
                fm[j + 4] = f2bf((aa + bb) * 0.5f);
                fp[j + 4] = f2bf(aa * bb);
                dd = aa - bb;
                fd[j + 4] = f2bf(dd * dd);
            }
            afrag[T][i]     = fm;   // mean      -> k in [0,128)
            afrag[T][i + 4] = fp;   // product   -> k in [128,256)
            afrag[T][i + 8] = fd;   // sq. diff  -> k in [256,384)
        }
    }

    float yp0[4] = {0.f, 0.f, 0.f, 0.f};
    float yp1[4] = {0.f, 0.f, 0.f, 0.f};

    // lane-invariant fragment base: W1f viewed as bf16x8[], entry (nt*12+s)*64 + lane
    const bf16x8* __restrict__ wb = (const bf16x8*)W1f;

    for (int nt = 0; nt < 48; ++nt) {
        f32x4 acc0 = {0.f, 0.f, 0.f, 0.f};
        f32x4 acc1 = {0.f, 0.f, 0.f, 0.f};
        const bf16x8* bp = wb + (nt * 12 << 6) + lane;
        #pragma unroll
        for (int s = 0; s < 12; ++s) {
            bf16x8 bfrag = bp[s << 6];   // global 16B/lane, coalesced, L1/L2-hit
            acc0 = __builtin_amdgcn_mfma_f32_16x16x32_bf16(afrag[0][s], bfrag, acc0, 0, 0, 0);
            acc1 = __builtin_amdgcn_mfma_f32_16x16x32_bf16(afrag[1][s], bfrag, acc1, 0, 0, 0);
        }

        // epilogue: D layout col=lane&15, row=quad*4+r (m89-verified)
        int ng = nt * 16 + m;
        float bias = b1[ng];
        float w2v  = W2[ng];
        #pragma unroll
        for (int r = 0; r < 4; ++r) {
            float h0 = acc0[r] + bias;
            float h1 = acc1[r] + bias;
            yp0[r] = fmaf(fmaxf(h0, 0.f), w2v, yp0[r]);
            yp1[r] = fmaf(fmaxf(h1, 0.f), w2v, yp1[r]);
        }
    }

    // reduce the 16 columns held across lanes of each quad-group
    #pragma unroll
    for (int off = 8; off >= 1; off >>= 1) {
        #pragma unroll
        for (int r = 0; r < 4; ++r) {
            yp0[r] += __shfl_xor(yp0[r], off, 64);
            yp1[r] += __shfl_xor(yp1[r], off, 64);
        }
    }
    if (m == 0) {
        float b2v = b2p[0];
        int e0 = eb + wave * 32 + quad * 4;
        #pragma unroll
        for (int r = 0; r < 4; ++r) {
            out[e0 + r]      = yp0[r] + b2v;
            out[e0 + 16 + r] = yp1[r] + b2v;
        }
    }
}

extern "C" void kernel_launch(void* const* d_in, const int* in_sizes, int n_in,
                              void* d_out, int out_size, void* d_ws, size_t ws_size,
                              hipStream_t stream) {
    const float* x  = (const float*)d_in[0];
    const int*   ei = (const int*)  d_in[1];
    // d_in[2]=edge_attr3, d_in[3]=edge_attr4, d_in[4]=batch : unused by reference
    const float* W1 = (const float*)d_in[5];
    const float* b1 = (const float*)d_in[6];
    const float* W2 = (const float*)d_in[7];
    const float* b2 = (const float*)d_in[8];
    short* W1f = (short*)d_ws;                 // 589824 B frag-major bf16 W1
    float* out = (float*)d_out;

    prep_w1<<<1152, 256, 0, stream>>>(W1, W1f);            // 294912 elems
    edge_mlp<<<3125, 256, 0, stream>>>(x, ei, b1, W2, b2, W1f, out);
}

// Round 13
// 352.438 us; speedup vs baseline: 3.1922x; 3.1922x over previous
//
#include <hip/hip_runtime.h>

#define EDGES 400000
#define DIM 128

typedef __attribute__((ext_vector_type(8))) short bf16x8;
typedef __attribute__((ext_vector_type(4))) float f32x4;

// fp32 -> bf16 round-to-nearest-even (no NaN handling needed here)
__device__ __forceinline__ short f2bf(float f) {
    unsigned u = __builtin_bit_cast(unsigned, f);
    unsigned r = (u + 0x7fffu + ((u >> 16) & 1u)) >> 16;
    return (short)r;
}

// Rearrange W1 [768][384] fp32 -> bf16 frag-major for 16x16x32 MFMA B-operand:
// frag (nt, s): lane holds B[k = (lane>>4)*8 + j][n = lane&15], k-step s, n-tile nt.
// W1f[((nt*12+s)*64+lane)*8 + j] = bf16( W1[(nt*16+(lane&15))*384 + s*32+(lane>>4)*8+j] )
__global__ void prep_w1(const float* __restrict__ W1, short* __restrict__ W1f) {
    int idx = blockIdx.x * 256 + threadIdx.x;       // 294912 = 48*12*64*8
    int j    = idx & 7;
    int lane = (idx >> 3) & 63;
    int fs   = idx >> 9;                            // nt*12 + s
    int s    = fs % 12;
    int nt   = fs / 12;
    int n = nt * 16 + (lane & 15);
    int k = s * 32 + (lane >> 4) * 8 + j;
    W1f[idx] = f2bf(W1[n * 384 + k]);
}

// Block: 256 threads = 4 waves, 128 edges (each wave owns 2 M-tiles of 16 edges).
// Round-0 structure (290us verified) with ONE change: 4 LDS buffers + one
// barrier per TWO nt (24 barriers vs 48). Evidence: round 0 is LDS-BW-bound
// (28.8 GB LDS reads -> 183us floor at 256B/cy/CU; measured 290us = 63% LDS
// efficiency; MFMA 114us hides under it). The recoverable slack is the per-nt
// __syncthreads vmcnt(0) drain + epilogue phase where the LDS pipe idles.
// Halving barrier frequency amortizes that drain. Compute path, numerics and
// accumulation order are IDENTICAL to round 0.
// (Round 10: wave rotation/setprio regressed. Round 11: dropping LDS for
// direct global B regressed 3.5x - LDS is the only path with enough BW.
// Rounds 1/7/9: >128-VGPR layouts spill; M_w=32 is the ceiling.)
__global__ __launch_bounds__(256, 2)
void edge_mlp(const float* __restrict__ x,
              const int*   __restrict__ ei,      // [2][EDGES]
              const float* __restrict__ b1,      // [768]
              const float* __restrict__ W2,      // [768]
              const float* __restrict__ b2p,     // [1]
              const short* __restrict__ W1f,     // frag-major bf16 W1
              float* __restrict__ out)           // [EDGES]
{
    __shared__ short sB[4][12 * 512];            // 4 x 12 frags x 1KB = 48 KB

    const int tid  = threadIdx.x;
    const int lane = tid & 63;
    const int wave = tid >> 6;
    const int m    = lane & 15;                  // A-row / B-col / D-col index
    const int quad = lane >> 4;
    const int eb   = blockIdx.x * 128;

    // ---- async stage nt 0 and 1 (12 frags each; each wave issues 3 per nt) ----
    #pragma unroll
    for (int jj = 0; jj < 3; ++jj) {
        int s = wave * 3 + jj;
        __builtin_amdgcn_global_load_lds(
            (const __attribute__((address_space(1))) void*)(W1f + (s << 9) + lane * 8),
            (__attribute__((address_space(3))) void*)(&sB[0][s << 9]),
            16, 0, 0);
        __builtin_amdgcn_global_load_lds(
            (const __attribute__((address_space(1))) void*)(W1f + 6144 + (s << 9) + lane * 8),
            (__attribute__((address_space(3))) void*)(&sB[1][s << 9]),
            16, 0, 0);
    }

    // ---- build A fragments in registers: 2 M-tiles x 12 K-steps (96 VGPRs) ----
    // A-frag layout (m89/m120-verified): lane holds A[m=lane&15][k=quad*8+j].
    // feat col kc = 32*s + 8*quad + j ; sections: s 0-3 mean, 4-7 prod, 8-11 sqdiff,
    // all three from the SAME x columns -> each x chunk loaded once.
    bf16x8 afrag[2][12];
    #pragma unroll
    for (int T = 0; T < 2; ++T) {
        int e = eb + wave * 32 + T * 16 + m;
        const float* r0 = x + (size_t)ei[e] * DIM;
        const float* r1 = x + (size_t)ei[EDGES + e] * DIM;
        #pragma unroll
        for (int i = 0; i < 4; ++i) {
            int c = i * 32 + quad * 8;
            f32x4 a0 = *(const f32x4*)(r0 + c);
            f32x4 a1 = *(const f32x4*)(r0 + c + 4);
            f32x4 c0 = *(const f32x4*)(r1 + c);
            f32x4 c1 = *(const f32x4*)(r1 + c + 4);
            bf16x8 fm, fp, fd;
            #pragma unroll
            for (int j = 0; j < 4; ++j) {
                float aa = a0[j], bb = c0[j];
                fm[j] = f2bf((aa + bb) * 0.5f);
                fp[j] = f2bf(aa * bb);
                float dd = aa - bb;
                fd[j] = f2bf(dd * dd);
                aa = a1[j]; bb = c1[j];
                fm[j + 4] = f2bf((aa + bb) * 0.5f);
                fp[j + 4] = f2bf(aa * bb);
                dd = aa - bb;
                fd[j + 4] = f2bf(dd * dd);
            }
            afrag[T][i]     = fm;   // mean      -> k in [0,128)
            afrag[T][i + 4] = fp;   // product   -> k in [128,256)
            afrag[T][i + 8] = fd;   // sq. diff  -> k in [256,384)
        }
    }

    float yp0[4] = {0.f, 0.f, 0.f, 0.f};
    float yp1[4] = {0.f, 0.f, 0.f, 0.f};

    __syncthreads();   // waits own global_load_lds (vmcnt) then barrier -> nt 0,1 ready

    for (int p = 0; p < 24; ++p) {
        const int nt0 = 2 * p;

        // prefetch pair (nt0+2, nt0+3) into the buffers read last iteration
        // (safe: post-barrier, all waves finished reading them)
        if (p < 23) {
            const short* srcA = W1f + (size_t)(nt0 + 2) * 6144;
            const short* srcB = W1f + (size_t)(nt0 + 3) * 6144;
            short* dstA = sB[(nt0 + 2) & 3];
            short* dstB = sB[(nt0 + 3) & 3];
            #pragma unroll
            for (int jj = 0; jj < 3; ++jj) {
                int s = wave * 3 + jj;
                __builtin_amdgcn_global_load_lds(
                    (const __attribute__((address_space(1))) void*)(srcA + (s << 9) + lane * 8),
                    (__attribute__((address_space(3))) void*)(dstA + (s << 9)),
                    16, 0, 0);
                __builtin_amdgcn_global_load_lds(
                    (const __attribute__((address_space(1))) void*)(srcB + (s << 9) + lane * 8),
                    (__attribute__((address_space(3))) void*)(dstB + (s << 9)),
                    16, 0, 0);
            }
        }

        // ---- two nt bodies per barrier period (identical to round-0 body) ----
        #pragma unroll
        for (int h = 0; h < 2; ++h) {
            const int nt = nt0 + h;
            f32x4 acc0 = {0.f, 0.f, 0.f, 0.f};
            f32x4 acc1 = {0.f, 0.f, 0.f, 0.f};
            const bf16x8* bp = (const bf16x8*)sB[nt & 3];
            #pragma unroll
            for (int s = 0; s < 12; ++s) {
                bf16x8 bfrag = bp[(s << 6) + lane];   // conflict-free: addr = s*1024 + lane*16
                acc0 = __builtin_amdgcn_mfma_f32_16x16x32_bf16(afrag[0][s], bfrag, acc0, 0, 0, 0);
                acc1 = __builtin_amdgcn_mfma_f32_16x16x32_bf16(afrag[1][s], bfrag, acc1, 0, 0, 0);
            }

            // epilogue: D layout col=lane&15, row=quad*4+r (m89-verified)
            int ng = nt * 16 + m;
            float bias = b1[ng];
            float w2v  = W2[ng];
            #pragma unroll
            for (int r = 0; r < 4; ++r) {
                float h0 = acc0[r] + bias;
                float h1 = acc1[r] + bias;
                yp0[r] = fmaf(fmaxf(h0, 0.f), w2v, yp0[r]);
                yp1[r] = fmaf(fmaxf(h1, 0.f), w2v, yp1[r]);
            }
        }

        __syncthreads();   // prefetch pair drained + all waves done with bufs of this pair
    }

    // reduce the 16 columns held across lanes of each quad-group
    #pragma unroll
    for (int off = 8; off >= 1; off >>= 1) {
        #pragma unroll
        for (int r = 0; r < 4; ++r) {
            yp0[r] += __shfl_xor(yp0[r], off, 64);
            yp1[r] += __shfl_xor(yp1[r], off, 64);
        }
    }
    if (m == 0) {
        float b2v = b2p[0];
        int e0 = eb + wave * 32 + quad * 4;
        #pragma unroll
        for (int r = 0; r < 4; ++r) {
            out[e0 + r]      = yp0[r] + b2v;
            out[e0 + 16 + r] = yp1[r] + b2v;
        }
    }
}

extern "C" void kernel_launch(void* const* d_in, const int* in_sizes, int n_in,
                              void* d_out, int out_size, void* d_ws, size_t ws_size,
                              hipStream_t stream) {
    const float* x  = (const float*)d_in[0];
    const int*   ei = (const int*)  d_in[1];
    // d_in[2]=edge_attr3, d_in[3]=edge_attr4, d_in[4]=batch : unused by reference
    const float* W1 = (const float*)d_in[5];
    const float* b1 = (const float*)d_in[6];
    const float* W2 = (const float*)d_in[7];
    const float* b2 = (const float*)d_in[8];
    short* W1f = (short*)d_ws;                 // 589824 B frag-major bf16 W1
    float* out = (float*)d_out;

    prep_w1<<<1152, 256, 0, stream>>>(W1, W1f);            // 294912 elems
    edge_mlp<<<3125, 256, 0, stream>>>(x, ei, b1, W2, b2, W1f, out);
}